// Round 10
// baseline (482.276 us; speedup 1.0000x reference)
//
#include <hip/hip_runtime.h>
#include <hip/hip_bf16.h>

// ---------------------------------------------------------------------------
// AttentionMIL: x[16,4096,1024] -> Linear+LN+ReLU -> Linear+LN+ReLU ->
//               attention (tanh linear -> scalar -> softmax over N) ->
//               weighted pool -> 2-layer classifier -> logits [16,2]
//
// Round 10: round-9 structure with the A-half1 staging bug fixed
// (gp + 2 elements -> gp + 32 elements). Fused-LN 128x512 tile, 512 thr /
// 8 waves (2Mx4N), BK=64. All loads compiler-tracked register loads:
//   - B (W^T, L2-hot) global->VGPR fragments, pipelined one k-half ahead.
//   - A reg-staged global->reg (1 step ahead) -> ds_write to 2x16KB dbuf.
// One lgkmcnt(0)+s_barrier per K-step (raw barrier: global loads in flight).
// ---------------------------------------------------------------------------

#define MTOT   65536
#define DDIM   1024
#define HDIM   512
#define NBAG   16
#define NINST  4096

#define BM 128
#define BK 64

typedef __attribute__((ext_vector_type(8))) short bf16x8;
typedef __attribute__((ext_vector_type(4))) float f32x4;

__device__ __forceinline__ unsigned short f2bf(float f) {
  __hip_bfloat16 h = __float2bfloat16(f);
  unsigned short u;
  __builtin_memcpy(&u, &h, 2);
  return u;
}
__device__ __forceinline__ float bf2f(unsigned short u) {
  unsigned int x = ((unsigned int)u) << 16;
  float f;
  __builtin_memcpy(&f, &x, 4);
  return f;
}

__device__ __forceinline__ bf16x8 pack8(float4 a, float4 b) {
  bf16x8 r;
  r[0] = (short)f2bf(a.x); r[1] = (short)f2bf(a.y);
  r[2] = (short)f2bf(a.z); r[3] = (short)f2bf(a.w);
  r[4] = (short)f2bf(b.x); r[5] = (short)f2bf(b.y);
  r[6] = (short)f2bf(b.z); r[7] = (short)f2bf(b.w);
  return r;
}

#define LKW0    asm volatile("s_waitcnt lgkmcnt(0)" ::: "memory")
#define BARRIER __builtin_amdgcn_s_barrier()

// ---------------------------------------------------------------------------
// transpose + cast f32 [R][C] -> bf16 [C][R]
// ---------------------------------------------------------------------------
__global__ void transpose_cast(const float* __restrict__ src,
                               __hip_bfloat16* __restrict__ dst,
                               int R, int C) {
  __shared__ float t[32][33];
  const int c0 = blockIdx.x * 32, r0 = blockIdx.y * 32;
  const int tx = threadIdx.x, ty = threadIdx.y;  // 32 x 8
#pragma unroll
  for (int i = 0; i < 32; i += 8)
    t[ty + i][tx] = src[(size_t)(r0 + ty + i) * C + c0 + tx];
  __syncthreads();
#pragma unroll
  for (int i = 0; i < 32; i += 8)
    dst[(size_t)(c0 + ty + i) * R + r0 + tx] = __float2bfloat16(t[tx][ty + i]);
}

// ---------------------------------------------------------------------------
// Fused GEMM: tile 128 rows x FULL 512 cols.  BT = W^T [512][KD] row-major.
// MODE 0: relu(LN(y+bias, g, b)) -> bf16 out.  MODE 1: tanh(y+bias).wa2+ba2.
// A LDS chunk layout (round-5-verified): half h (0/1) has 8 chunks of
// 16 rows x 32 k (1KB). Staging: wave w stages chunk w of each half; lane l
// holds (row = w*16 + (l&15), kslot = (l>>4)^(l&3)) at byte 16*l. Fragment
// read offset l16*8 + ((lg^(l16&3))<<7) elems: bank-clean (0 conflicts).
// B fragments: global->reg 16B loads, row = wn*128+fn*16+l16, k = h*32+lg*8.
// ---------------------------------------------------------------------------
template <int KD, bool AF32, int MODE>
__global__ __launch_bounds__(512, 2)
void gemm_fused(const void* Ap, const __hip_bfloat16* __restrict__ BT,
                const float* __restrict__ bias, const float* __restrict__ gg,
                const float* __restrict__ bb, const float* __restrict__ wa2,
                const float* __restrict__ ba2,
                __hip_bfloat16* __restrict__ outh, float* __restrict__ outs) {
  __shared__ __align__(16) char smem[32768];  // A double buffer 2 x 16KB

  const int tid  = threadIdx.x;   // 512
  const int lane = tid & 63;
  const int w    = tid >> 6;      // 8 waves
  const int wm   = w >> 2;        // 0..1
  const int wn   = w & 3;         // 0..3
  const int l16  = lane & 15;
  const int lg   = lane >> 4;     // 0..3
  const size_t row0 = (size_t)blockIdx.x * BM;

  const int rSt = w * 16 + (lane & 15);        // staged global row (0..127)
  const int sS  = (lane >> 4) ^ (lane & 3);    // pre-swizzled k-slot
  const int frag_off = l16 * 8 + ((lg ^ (l16 & 3)) << 7);

  constexpr int NT = KD / BK;  // 16 (GEMM1) / 8 (GEMM2,3)
  const __hip_bfloat16* Abf = (const __hip_bfloat16*)Ap;
  const float* Af32 = (const float*)Ap;

  f32x4 acc[4][8];
#pragma unroll
  for (int i = 0; i < 4; i++)
#pragma unroll
    for (int j = 0; j < 8; j++) acc[i][j] = (f32x4){0.f, 0.f, 0.f, 0.f};

  auto ldsA = [&](int buf) -> __hip_bfloat16* {
    return (__hip_bfloat16*)(smem + buf * 16384);
  };

  // ---- A reg staging (compiler-tracked loads) ----
  float4 rf0, rf1, rf2, rf3;  // AF32: 16 f32
  int4 rb0, rb1;              // bf16: 2 x 8 bf16 (k-half0 slot, k-half1 slot)
  auto loadA = [&](int t) {
    if constexpr (AF32) {
      const float* gp = Af32 + (row0 + rSt) * KD + t * BK + sS * 8;
      rf0 = *(const float4*)gp;          // k = sS*8 .. +3        (half0)
      rf1 = *(const float4*)(gp + 4);    // k = sS*8+4 .. +7      (half0)
      rf2 = *(const float4*)(gp + 32);   // k = 32+sS*8 .. +3     (half1)
      rf3 = *(const float4*)(gp + 36);   // k = 32+sS*8+4 .. +7   (half1)
    } else {
      const __hip_bfloat16* gp = Abf + (row0 + rSt) * KD + t * BK + sS * 8;
      rb0 = *(const int4*)gp;            // k = sS*8 .. +7        (half0)
      rb1 = *(const int4*)(gp + 32);     // k = 32+sS*8 .. +7     (half1) [FIX]
    }
  };
  auto writeA = [&](int buf) {
    __hip_bfloat16* d0 = ldsA(buf) + (0 * 8 + w) * 512 + lane * 8;
    __hip_bfloat16* d1 = ldsA(buf) + (1 * 8 + w) * 512 + lane * 8;
    if constexpr (AF32) {
      *reinterpret_cast<bf16x8*>(d0) = pack8(rf0, rf1);
      *reinterpret_cast<bf16x8*>(d1) = pack8(rf2, rf3);
    } else {
      *reinterpret_cast<int4*>(d0) = rb0;
      *reinterpret_cast<int4*>(d1) = rb1;
    }
  };

  // ---- B fragment loads: global -> VGPR (compiler-tracked) ----
  bf16x8 b0[8], b1[8];
  auto loadB = [&](bf16x8* b, int t, int h) {
#pragma unroll
    for (int fn = 0; fn < 8; fn++)
      b[fn] = *reinterpret_cast<const bf16x8*>(
          BT + (size_t)(wn * 128 + fn * 16 + l16) * KD + t * BK + h * 32 +
          lg * 8);
  };
  auto rdA = [&](bf16x8* af, int buf, int h) {
#pragma unroll
    for (int f = 0; f < 4; f++)
      af[f] = *reinterpret_cast<const bf16x8*>(
          ldsA(buf) + (h * 8 + wm * 4 + f) * 512 + frag_off);
  };

#define MFMA8x4(AF, B)                                                         \
  _Pragma("unroll") for (int f_ = 0; f_ < 4; f_++)                             \
  _Pragma("unroll") for (int n_ = 0; n_ < 8; n_++)                             \
      acc[f_][n_] = __builtin_amdgcn_mfma_f32_16x16x32_bf16(                   \
          AF[f_], B[n_], acc[f_][n_], 0, 0, 0);

  // ---- prologue ----
  loadA(0);
  loadB(b0, 0, 0);
  writeA(0);           // compiler waits A(0) regs
  if (NT > 1) loadA(1);
  LKW0;
  BARRIER;

  // ---- main loop: 1 barrier / K-step, zero manual vmcnt ----
  for (int t = 0; t < NT; ++t) {
    const int cur = t & 1, nxt = cur ^ 1;
    loadB(b1, t, 1);                  // B(t) k-half1 (used after half0 MFMAs)
    if (t + 1 < NT) writeA(nxt);      // A(t+1) regs -> LDS[nxt]
    bf16x8 af[4];
    rdA(af, cur, 0);
    if (t + 2 < NT) loadA(t + 2);     // A(t+2) -> regs (HBM cover ~1 step)
    __builtin_amdgcn_s_setprio(1);
    MFMA8x4(af, b0)
    __builtin_amdgcn_s_setprio(0);
    if (t + 1 < NT) loadB(b0, t + 1, 0);  // B(t+1) half0 (cover ~1/2 step)
    rdA(af, cur, 1);
    __builtin_amdgcn_s_setprio(1);
    MFMA8x4(af, b1)
    __builtin_amdgcn_s_setprio(0);
    LKW0;     // retire my ds_reads + ds_writes
    BARRIER;  // raw barrier: outstanding global loads stay in flight
  }
#undef MFMA8x4

  // ---------------- epilogue (round-2-verified, full-width LN) ----------
  __syncthreads();
  float (*redS)[4] = (float(*)[4])smem;            // 2 KB
  float (*redQ)[4] = (float(*)[4])(smem + 2048);   // 2 KB
  float* muL = (float*)(smem + 4096);
  float* rsL = (float*)(smem + 4608);

  float biasv[8];
#pragma unroll
  for (int fn = 0; fn < 8; fn++) biasv[fn] = bias[wn * 128 + fn * 16 + l16];

  if (MODE == 0) {
    float gv[8], bv[8];
#pragma unroll
    for (int fn = 0; fn < 8; fn++) {
      const int col = wn * 128 + fn * 16 + l16;
      gv[fn] = gg[col];
      bv[fn] = bb[col];
    }
#pragma unroll
    for (int fm = 0; fm < 4; fm++)
#pragma unroll
      for (int r = 0; r < 4; r++) {
        float s1 = 0.f, s2 = 0.f;
#pragma unroll
        for (int fn = 0; fn < 8; fn++) {
          const float v = acc[fm][fn][r] + biasv[fn];
          s1 += v;
          s2 += v * v;
        }
#pragma unroll
        for (int m = 1; m < 16; m <<= 1) {
          s1 += __shfl_xor(s1, m);
          s2 += __shfl_xor(s2, m);
        }
        if (l16 == 0) {
          const int rl = wm * 64 + fm * 16 + lg * 4 + r;
          redS[rl][wn] = s1;
          redQ[rl][wn] = s2;
        }
      }
    __syncthreads();
    if (tid < BM) {
      const float S = redS[tid][0] + redS[tid][1] + redS[tid][2] + redS[tid][3];
      const float Q = redQ[tid][0] + redQ[tid][1] + redQ[tid][2] + redQ[tid][3];
      const float mean = S * (1.f / 512.f);
      const float var = Q * (1.f / 512.f) - mean * mean;
      muL[tid] = mean;
      rsL[tid] = rsqrtf(var + 1e-5f);
    }
    __syncthreads();
#pragma unroll
    for (int fm = 0; fm < 4; fm++)
#pragma unroll
      for (int r = 0; r < 4; r++) {
        const int rl = wm * 64 + fm * 16 + lg * 4 + r;
        const float mu = muL[rl], rs = rsL[rl];
#pragma unroll
        for (int fn = 0; fn < 8; fn++) {
          const float v = acc[fm][fn][r] + biasv[fn];
          float y = (v - mu) * rs * gv[fn] + bv[fn];
          y = fmaxf(y, 0.f);
          outh[(row0 + rl) * HDIM + wn * 128 + fn * 16 + l16] =
              __float2bfloat16(y);
        }
      }
  } else {
    float wv[8];
#pragma unroll
    for (int fn = 0; fn < 8; fn++) wv[fn] = wa2[wn * 128 + fn * 16 + l16];
#pragma unroll
    for (int fm = 0; fm < 4; fm++)
#pragma unroll
      for (int r = 0; r < 4; r++) {
        float s = 0.f;
#pragma unroll
        for (int fn = 0; fn < 8; fn++) {
          const float v = acc[fm][fn][r] + biasv[fn];
          s += tanhf(v) * wv[fn];
        }
#pragma unroll
        for (int m = 1; m < 16; m <<= 1) s += __shfl_xor(s, m);
        if (l16 == 0) redS[wm * 64 + fm * 16 + lg * 4 + r][wn] = s;
      }
    __syncthreads();
    if (tid < BM) {
      outs[row0 + tid] =
          redS[tid][0] + redS[tid][1] + redS[tid][2] + redS[tid][3] + ba2[0];
    }
  }
}

// ---------------------------------------------------------------------------
// softmax over 4096 instances per bag
// ---------------------------------------------------------------------------
__global__ void softmax_bag(const float* __restrict__ sc, float* __restrict__ at) {
  const int b = blockIdx.x;
  const int tid = threadIdx.x;  // 256
  const int lane = tid & 63, w = tid >> 6;
  const float* s = sc + (size_t)b * NINST;
  float v[16];
  float mx = -1e30f;
#pragma unroll
  for (int i = 0; i < 16; i++) {
    v[i] = s[tid + i * 256];
    mx = fmaxf(mx, v[i]);
  }
#pragma unroll
  for (int off = 32; off; off >>= 1) mx = fmaxf(mx, __shfl_xor(mx, off));
  __shared__ float red[4];
  if (lane == 0) red[w] = mx;
  __syncthreads();
  mx = fmaxf(fmaxf(red[0], red[1]), fmaxf(red[2], red[3]));
  float sum = 0.f;
#pragma unroll
  for (int i = 0; i < 16; i++) {
    v[i] = expf(v[i] - mx);
    sum += v[i];
  }
#pragma unroll
  for (int off = 32; off; off >>= 1) sum += __shfl_xor(sum, off);
  __shared__ float red2[4];
  if (lane == 0) red2[w] = sum;
  __syncthreads();
  sum = red2[0] + red2[1] + red2[2] + red2[3];
  const float inv = 1.f / sum;
#pragma unroll
  for (int i = 0; i < 16; i++) at[(size_t)b * NINST + tid + i * 256] = v[i] * inv;
}

// ---------------------------------------------------------------------------
// pooled[b,h] = sum_n attn[b,n] * h2[b,n,h]
// ---------------------------------------------------------------------------
__global__ void pooled_partial(const __hip_bfloat16* __restrict__ h2,
                               const float* __restrict__ at,
                               float* __restrict__ part) {
  const int bid = blockIdx.x;
  const int b = bid >> 5, cc = (bid >> 3) & 3, nch = bid & 7;
  const int tid = threadIdx.x;  // 256
  const int c4 = (tid & 31) * 4, sub = tid >> 5;
  const int n0 = nch * 512;
  const size_t base = (size_t)b * NINST;
  float a0 = 0.f, a1 = 0.f, a2 = 0.f, a3 = 0.f;
  for (int n = n0 + sub; n < n0 + 512; n += 8) {
    const float a = at[base + n];
    const ushort4 u = *reinterpret_cast<const ushort4*>(
        &h2[(base + n) * HDIM + cc * 128 + c4]);
    a0 += a * bf2f(u.x);
    a1 += a * bf2f(u.y);
    a2 += a * bf2f(u.z);
    a3 += a * bf2f(u.w);
  }
  __shared__ float pb[8][128];
  pb[sub][c4 + 0] = a0;
  pb[sub][c4 + 1] = a1;
  pb[sub][c4 + 2] = a2;
  pb[sub][c4 + 3] = a3;
  __syncthreads();
  if (tid < 128) {
    float s = 0.f;
#pragma unroll
    for (int j = 0; j < 8; j++) s += pb[j][tid];
    part[(size_t)nch * 8192 + b * 512 + cc * 128 + tid] = s;
  }
}

__global__ void pooled_reduce(const float* __restrict__ part,
                              float* __restrict__ pooled) {
  const int i = blockIdx.x * 256 + threadIdx.x;  // 8192 total
  float s = 0.f;
#pragma unroll
  for (int j = 0; j < 8; j++) s += part[(size_t)j * 8192 + i];
  pooled[i] = s;
}

// ---------------------------------------------------------------------------
// classifier
// ---------------------------------------------------------------------------
__global__ void classifier(const float* __restrict__ pooled,
                           const float* __restrict__ Wc1,
                           const float* __restrict__ bc1,
                           const float* __restrict__ Wc2,
                           const float* __restrict__ bc2,
                           float* __restrict__ out) {
  __shared__ float P[NBAG][512];
  __shared__ float Rb[NBAG][512];
  const int tid = threadIdx.x;  // 512
#pragma unroll
  for (int i = 0; i < NBAG; i++) P[i][tid] = pooled[i * 512 + tid];
  __syncthreads();
  float r[NBAG];
#pragma unroll
  for (int i = 0; i < NBAG; i++) r[i] = 0.f;
  for (int k = 0; k < 512; k++) {
    const float wv = Wc1[k * 512 + tid];
#pragma unroll
    for (int i = 0; i < NBAG; i++) r[i] += P[i][k] * wv;
  }
#pragma unroll
  for (int i = 0; i < NBAG; i++) Rb[i][tid] = fmaxf(r[i] + bc1[tid], 0.f);
  __syncthreads();
  if (tid < 32) {
    const int i = tid >> 1, c = tid & 1;
    float s = bc2[c];
    for (int k = 0; k < 512; k++) s += Rb[i][k] * Wc2[k * 2 + c];
    out[i * 2 + c] = s;
  }
}

// ---------------------------------------------------------------------------
extern "C" void kernel_launch(void* const* d_in, const int* in_sizes, int n_in,
                              void* d_out, int out_size, void* d_ws,
                              size_t ws_size, hipStream_t stream) {
  const float* x   = (const float*)d_in[0];
  const float* W1  = (const float*)d_in[1];
  const float* b1  = (const float*)d_in[2];
  const float* g1  = (const float*)d_in[3];
  const float* be1 = (const float*)d_in[4];
  const float* W2  = (const float*)d_in[5];
  const float* b2  = (const float*)d_in[6];
  const float* g2  = (const float*)d_in[7];
  const float* be2 = (const float*)d_in[8];
  const float* Wa1 = (const float*)d_in[9];
  const float* ba1 = (const float*)d_in[10];
  const float* wa2 = (const float*)d_in[11];
  const float* ba2 = (const float*)d_in[12];
  const float* Wc1 = (const float*)d_in[13];
  const float* bc1 = (const float*)d_in[14];
  const float* Wc2 = (const float*)d_in[15];
  const float* bc2 = (const float*)d_in[16];
  float* out = (float*)d_out;

  char* ws = (char*)d_ws;
  __hip_bfloat16* W1T = (__hip_bfloat16*)(ws + 0);          // 1 MB
  __hip_bfloat16* W2T = (__hip_bfloat16*)(ws + 1048576);    // 512 KB
  __hip_bfloat16* WaT = (__hip_bfloat16*)(ws + 1572864);    // 512 KB
  float* scores = (float*)(ws + 2097152);                   // 256 KB
  float* attn   = (float*)(ws + 2359296);                   // 256 KB
  float* part   = (float*)(ws + 2621440);                   // 256 KB
  float* pooled = (float*)(ws + 2883584);                   // 32 KB
  __hip_bfloat16* hbuf = (__hip_bfloat16*)(ws + 4194304);   // 64 MB (h1/h2)

  transpose_cast<<<dim3(16, 32), dim3(32, 8), 0, stream>>>(W1, W1T, DDIM, HDIM);
  transpose_cast<<<dim3(16, 16), dim3(32, 8), 0, stream>>>(W2, W2T, HDIM, HDIM);
  transpose_cast<<<dim3(16, 16), dim3(32, 8), 0, stream>>>(Wa1, WaT, HDIM, HDIM);

  const int grid = MTOT / BM;  // 512

  // GEMM1: h1 = relu(LN(x @ W1 + b1))
  gemm_fused<DDIM, true, 0><<<grid, 512, 0, stream>>>(
      x, W1T, b1, g1, be1, nullptr, nullptr, hbuf, nullptr);
  // GEMM2: h2 = relu(LN(h1 @ W2 + b2))  (in-place: block-local rows)
  gemm_fused<HDIM, false, 0><<<grid, 512, 0, stream>>>(
      hbuf, W2T, b2, g2, be2, nullptr, nullptr, hbuf, nullptr);
  // GEMM3: scores = tanh(h2 @ Wa1 + ba1) . wa2 + ba2
  gemm_fused<HDIM, false, 1><<<grid, 512, 0, stream>>>(
      hbuf, WaT, ba1, nullptr, nullptr, wa2, ba2, nullptr, scores);

  softmax_bag<<<NBAG, 256, 0, stream>>>(scores, attn);
  pooled_partial<<<512, 256, 0, stream>>>(hbuf, attn, part);
  pooled_reduce<<<32, 256, 0, stream>>>(part, pooled);
  classifier<<<1, 512, 0, stream>>>(pooled, Wc1, bc1, Wc2, bc2, out);
}